// Round 1
// 338.592 us; speedup vs baseline: 1.0207x; 1.0207x over previous
//
#include <hip/hip_runtime.h>

using u16 = unsigned short;
using u32 = unsigned int;

typedef __attribute__((ext_vector_type(4))) float f32x4;
typedef __attribute__((ext_vector_type(8))) short s16x8;

__device__ __forceinline__ u16 f2b(float f) {
  u32 u = __builtin_bit_cast(u32, f);
  u += 0x7FFFu + ((u >> 16) & 1u);
  return (u16)(u >> 16);
}
__device__ __forceinline__ float b2f(u16 h) {
  return __builtin_bit_cast(float, (u32)h << 16);
}
__device__ __forceinline__ void gl_lds16(const void* g, void* l) {
  __builtin_amdgcn_global_load_lds(
      (const __attribute__((address_space(1))) void*)g,
      (__attribute__((address_space(3))) void*)l, 16, 0, 0);
}
template<int N> __device__ __forceinline__ void waitvm() {
  static_assert(N == 8 || N == 6 || N == 4 || N == 3 || N == 0, "literal");
  if constexpr (N == 8)      asm volatile("s_waitcnt vmcnt(8)" ::: "memory");
  else if constexpr (N == 6) asm volatile("s_waitcnt vmcnt(6)" ::: "memory");
  else if constexpr (N == 4) asm volatile("s_waitcnt vmcnt(4)" ::: "memory");
  else if constexpr (N == 3) asm volatile("s_waitcnt vmcnt(3)" ::: "memory");
  else                       asm volatile("s_waitcnt vmcnt(0)" ::: "memory");
}
// raw barrier (no vmcnt/lgkmcnt drain) + compiler memory fence so no LDS
// read / global_load_lds can be moved across it by the optimizer.
__device__ __forceinline__ void barrier_np() {
  __builtin_amdgcn_s_barrier();
  asm volatile("" ::: "memory");
}

// ---- fused fp32 -> bf16 conversion: x | Wq | Wk | Wv -> contiguous dst ------
__global__ __launch_bounds__(256) void convert4_k(
    const float* __restrict__ x, const float* __restrict__ Wq,
    const float* __restrict__ Wk, const float* __restrict__ Wv,
    u16* __restrict__ dst) {
  long g = (long)(blockIdx.x * 256 + threadIdx.x) * 8;   // 8-elem chunks
  const float* s;
  if (g < 8388608L)       s = x  + g;
  else if (g < 9437184L)  s = Wq + (g - 8388608L);
  else if (g < 10485760L) s = Wk + (g - 9437184L);
  else                    s = Wv + (g - 10485760L);
  f32x4 lo = *(const f32x4*)s;
  f32x4 hi = *(const f32x4*)(s + 4);
  s16x8 o;
  #pragma unroll
  for (int e = 0; e < 4; ++e) { o[e] = (short)f2b(lo[e]); o[4 + e] = (short)f2b(hi[e]); }
  *(s16x8*)(dst + g) = o;
}

// ---- NT GEMM, (32*MREP)x256 tile, BK=32, 4-buffer LDS ring, counted vmcnt ---
// Schedule (T3+T4+T5): per K-tile T:
//   waitvm<2*CALLS>  -> own loads for tile T landed (only T+1,T+2 in flight)
//   s_barrier        -> ALL waves' loads for tile T landed (vmcnt is per-wave)
//   stage(T+3)       -> writes buf[(T-1)&3]; its readers (tile T-1) finished
//                       before this barrier  => WAR-safe by construction
//   compute(T)       -> 4 B-frag + MREP A-frag ds_read_b128, MREP*4 MFMA
// vmcnt never drains to 0 in the main loop; tail drains 2*CALLS -> CALLS -> 0.
// LDS chunk (row,kc) holds global 16B chunk (row, kc ^ (row&3)): spreads the
// b128 reads over all 8 four-bank groups (same conflict-free profile the
// profiled kernel measured: SQ_LDS_BANK_CONFLICT = 0).
// EPI 0: QKV proj (+bias; bf16 Q[b][s][h], K[b][s][h], Vt[b][d][s]).
// EPI 1: scores (*1/32, mask==0 -> -inf).  EPI 2: PV -> fp32 out.
template<int EPI, int MREP>
__global__ __launch_bounds__(512, 2) void gemm_nt(
    const u16* __restrict__ A, const u16* __restrict__ B0,
    const u16* __restrict__ W2, const u16* __restrict__ W3,
    int lda, int ldb, int K, long za, long zb, long ze,
    const float* __restrict__ bq, const float* __restrict__ bk, const float* __restrict__ bv,
    u16* __restrict__ qw, u16* __restrict__ kw, u16* __restrict__ vt,
    const int* __restrict__ mask, u16* __restrict__ sc, float* __restrict__ outO)
{
  constexpr int BM    = 32 * MREP;       // 128 or 256
  constexpr int ACH   = BM * 4;          // A 16B-chunks per K-tile (4/row)
  constexpr int CH    = ACH + 1024;      // + B: 256 rows * 4 chunks
  constexpr int CALLS = CH / 512;        // 3 (MREP=4) or 4 (MREP=8)
  constexpr int BUF   = CH * 8;          // u16 per ring slot (CH*16 bytes)
  __shared__ __align__(16) u16 lds[4 * BUF];   // 96 KB or 128 KB -> 1 block/CU

  const int tid  = threadIdx.x;
  const int wave = tid >> 6, lane = tid & 63;
  const int wr = wave >> 2, wc = wave & 3;          // 2 x 4 wave grid
  const int m0 = blockIdx.y * BM, n0 = blockIdx.x * 256;
  const long z = blockIdx.z;
  A += z * za;

  const u16* Bsrc = B0;
  int nbase = n0;
  if constexpr (EPI == 0) {
    Bsrc = (n0 < 1024) ? B0 : (n0 < 2048) ? W2 : W3;
    nbase = n0 & 1023;
  }
  Bsrc += z * zb;

  // per-call staging source pointers (at k=0) and linear LDS offsets.
  // global source is per-lane (swizzled); LDS dest is linear (HW lane*16B).
  const u16* gsrc[CALLS];
  u32 loff[CALLS];
  #pragma unroll
  for (int call = 0; call < CALLS; ++call) {
    int qq  = call * 512 + tid;          // 16B chunk id within tile
    int isB = qq >= ACH;
    int r   = (isB ? qq - ACH : qq) >> 2;
    int kc  = (qq & 3) ^ (r & 3);        // XOR-swizzled source chunk
    gsrc[call] = isB ? (Bsrc + (size_t)(nbase + r) * ldb + kc * 8)
                     : (A    + (size_t)(m0    + r) * lda + kc * 8);
    loff[call] = (u32)qq * 8;
  }

  // fragment read offsets (u16 units, relative to ring-slot base)
  const int frow = lane & 15;            // m (or n) index within 16x16 tile
  const int q    = lane >> 4;            // k-quarter (8 elems)
  u32 aoff[MREP], boff[4];
  #pragma unroll
  for (int i = 0; i < MREP; ++i) {
    int lr = wr * (16 * MREP) + i * 16 + frow;
    aoff[i] = (u32)lr * 32 + (u32)((q ^ (lr & 3)) << 3);
  }
  #pragma unroll
  for (int j = 0; j < 4; ++j) {
    int lc = wc * 64 + j * 16 + frow;
    boff[j] = (u32)ACH * 8 + (u32)lc * 32 + (u32)((q ^ (lc & 3)) << 3);
  }

  f32x4 acc[MREP][4];
  const f32x4 fz = {0.f, 0.f, 0.f, 0.f};
  #pragma unroll
  for (int i = 0; i < MREP; ++i)
    #pragma unroll
    for (int j = 0; j < 4; ++j) acc[i][j] = fz;

  const int NT = K >> 5;                 // BK=32 tiles; NT >= 32 here

  auto stage = [&](int t) {
    u16* buf = lds + (size_t)(t & 3) * BUF;
    #pragma unroll
    for (int call = 0; call < CALLS; ++call)
      gl_lds16(gsrc[call] + (size_t)t * 32, buf + loff[call]);
  };
  auto comp = [&](int t) {
    const u16* buf = lds + (size_t)(t & 3) * BUF;
    s16x8 bf[4];
    #pragma unroll
    for (int j = 0; j < 4; ++j) bf[j] = *(const s16x8*)(buf + boff[j]);
    __builtin_amdgcn_s_setprio(1);
    #pragma unroll
    for (int i = 0; i < MREP; ++i) {
      s16x8 af = *(const s16x8*)(buf + aoff[i]);
      #pragma unroll
      for (int j = 0; j < 4; ++j)
        acc[i][j] = __builtin_amdgcn_mfma_f32_16x16x32_bf16(af, bf[j], acc[i][j], 0, 0, 0);
    }
    __builtin_amdgcn_s_setprio(0);
  };

  stage(0); stage(1); stage(2);          // prologue: 3 tiles in flight
  for (int T = 0; T < NT - 3; ++T) {
    waitvm<2 * CALLS>();                 // tile T landed (mine)
    barrier_np();                        // tile T landed (everyone's)
    stage(T + 3);                        // overwrites buf[(T-1)&3]: safe
    comp(T);
  }
  waitvm<2 * CALLS>(); barrier_np(); comp(NT - 3);
  waitvm<CALLS>();     barrier_np(); comp(NT - 2);
  waitvm<0>();         barrier_np(); comp(NT - 1);

  // epilogue: C/D layout col=lane&15, row=(lane>>4)*4+reg  (m89-verified)
  const int r0 = (lane >> 4) * 4;
  const int ccol = lane & 15;
  #pragma unroll
  for (int i = 0; i < MREP; ++i) {
    #pragma unroll
    for (int j = 0; j < 4; ++j) {
      #pragma unroll
      for (int r = 0; r < 4; ++r) {
        int R = m0 + wr * (16 * MREP) + i * 16 + r0 + r;  // row: (b,)s / q idx
        int C = n0 + wc * 64 + j * 16 + ccol;             // col: feature/k/d
        float v = acc[i][j][r];
        if constexpr (EPI == 0) {
          int sec = C >> 10, nl = C & 1023;
          v += (sec == 0) ? bq[nl] : (sec == 1) ? bk[nl] : bv[nl];
          u16 o = f2b(v);
          int b = R >> 11, s = R & 2047;
          if (sec == 0)      qw[(size_t)R * 1024 + nl] = o;               // Q[b][s][h]
          else if (sec == 1) kw[(size_t)R * 1024 + nl] = o;               // K[b][s][h]
          else               vt[(size_t)b * 2097152u + (size_t)nl * 2048 + s] = o; // Vt[b][d][s]
        } else if constexpr (EPI == 1) {
          v *= 0.03125f;  // 1/sqrt(1024)
          size_t idx = (size_t)(z * ze) + (size_t)R * 2048 + C;
          if (mask[idx] == 0) v = -__builtin_inff();
          sc[idx] = f2b(v);
        } else {
          outO[(size_t)(z * ze) + (size_t)R * 1024 + C] = v;   // fp32 out
        }
      }
    }
  }
}

// ---- row softmax over 2048 bf16, in place, fp32 internal --------------------
__global__ __launch_bounds__(256) void softmax_k(u16* __restrict__ Sc) {
  __shared__ float red[8];
  u16* p = Sc + (size_t)blockIdx.x * 2048;
  const int tid = threadIdx.x;
  const int lane = tid & 63, wv = tid >> 6;
  s16x8 u = *(const s16x8*)(p + tid * 8);
  float v[8];
  #pragma unroll
  for (int e = 0; e < 8; ++e) v[e] = b2f((u16)u[e]);
  float mx = v[0];
  #pragma unroll
  for (int e = 1; e < 8; ++e) mx = fmaxf(mx, v[e]);
  #pragma unroll
  for (int off = 32; off > 0; off >>= 1) mx = fmaxf(mx, __shfl_xor(mx, off));
  if (lane == 0) red[wv] = mx;
  __syncthreads();
  mx = fmaxf(fmaxf(red[0], red[1]), fmaxf(red[2], red[3]));
  float s = 0.f;
  #pragma unroll
  for (int e = 0; e < 8; ++e) { v[e] = __expf(v[e] - mx); s += v[e]; }
  #pragma unroll
  for (int off = 32; off > 0; off >>= 1) s += __shfl_xor(s, off);
  if (lane == 0) red[4 + wv] = s;
  __syncthreads();
  s = (red[4] + red[5]) + (red[6] + red[7]);
  float inv = 1.f / s;
  s16x8 o;
  #pragma unroll
  for (int e = 0; e < 8; ++e) o[e] = (short)f2b(v[e] * inv);
  *(s16x8*)(p + tid * 8) = o;
}

extern "C" void kernel_launch(void* const* d_in, const int* in_sizes, int n_in,
                              void* d_out, int out_size, void* d_ws, size_t ws_size,
                              hipStream_t stream) {
  const float* x  = (const float*)d_in[0];
  const int* mask = (const int*)d_in[1];
  const float* Wq = (const float*)d_in[2];
  const float* bq = (const float*)d_in[3];
  const float* Wk = (const float*)d_in[4];
  const float* bk = (const float*)d_in[5];
  const float* Wv = (const float*)d_in[6];
  const float* bv = (const float*)d_in[7];
  float* out = (float*)d_out;
  char* ws = (char*)d_ws;   // ws_size >= 104 MB established previously

  u16* xc  = (u16*)ws;                   // [8192][1024]  16 MB
  u16* Wqc = (u16*)(ws + (16u << 20));   // 2 MB each (contiguous after xc)
  u16* Wkc = (u16*)(ws + (18u << 20));
  u16* Wvc = (u16*)(ws + (20u << 20));
  u16* Qw  = (u16*)(ws + (22u << 20));   // [4][2048][1024] 16 MB
  u16* Kw  = (u16*)(ws + (38u << 20));   // 16 MB
  u16* Vt  = (u16*)(ws + (54u << 20));   // [4][1024][2048] 16 MB
  u16* Sc  = (u16*)(ws + (70u << 20));   // [4][2048][2048] 32 MB -> 102 MB

  convert4_k<<<5632, 256, 0, stream>>>(x, Wq, Wk, Wv, xc);

  // QKV: M=8192 (b,s), N=3072 (q|k|v), K=1024.  128x256 tiles -> 768 blocks
  gemm_nt<0, 4><<<dim3(12, 64, 1), 512, 0, stream>>>(
      xc, Wqc, Wkc, Wvc, 1024, 1024, 1024, 0, 0, 0,
      bq, bk, bv, Qw, Kw, Vt, nullptr, nullptr, nullptr);
  // scores: per-z M=2048 (q), N=2048 (k), K=1024.  256x256 -> 256 blocks
  gemm_nt<1, 8><<<dim3(8, 8, 4), 512, 0, stream>>>(
      Qw, Kw, nullptr, nullptr, 1024, 1024, 1024, 2097152, 2097152, 4194304,
      nullptr, nullptr, nullptr, nullptr, nullptr, nullptr, mask, Sc, nullptr);
  softmax_k<<<8192, 256, 0, stream>>>(Sc);
  // PV: per-z M=2048 (q), N=1024 (d), K=2048.  128x256 -> 256 blocks
  gemm_nt<2, 4><<<dim3(4, 16, 4), 512, 0, stream>>>(
      Sc, Vt, nullptr, nullptr, 2048, 2048, 2048, 4194304, 2097152, 2097152,
      nullptr, nullptr, nullptr, nullptr, nullptr, nullptr, nullptr, nullptr, out);
}

// Round 2
// 330.672 us; speedup vs baseline: 1.0451x; 1.0240x over previous
//
#include <hip/hip_runtime.h>

using u16 = unsigned short;
using u32 = unsigned int;

typedef __attribute__((ext_vector_type(4))) float f32x4;
typedef __attribute__((ext_vector_type(8))) short s16x8;

__device__ __forceinline__ u16 f2b(float f) {
  u32 u = __builtin_bit_cast(u32, f);
  u += 0x7FFFu + ((u >> 16) & 1u);
  return (u16)(u >> 16);
}
__device__ __forceinline__ float b2f(u16 h) {
  return __builtin_bit_cast(float, (u32)h << 16);
}
__device__ __forceinline__ void gl_lds16(const void* g, void* l) {
  __builtin_amdgcn_global_load_lds(
      (const __attribute__((address_space(1))) void*)g,
      (__attribute__((address_space(3))) void*)l, 16, 0, 0);
}
template<int N> __device__ __forceinline__ void waitvm() {
  static_assert(N == 8 || N == 6 || N == 4 || N == 3 || N == 0, "literal");
  if constexpr (N == 8)      asm volatile("s_waitcnt vmcnt(8)" ::: "memory");
  else if constexpr (N == 6) asm volatile("s_waitcnt vmcnt(6)" ::: "memory");
  else if constexpr (N == 4) asm volatile("s_waitcnt vmcnt(4)" ::: "memory");
  else if constexpr (N == 3) asm volatile("s_waitcnt vmcnt(3)" ::: "memory");
  else                       asm volatile("s_waitcnt vmcnt(0)" ::: "memory");
}
// raw barrier + compiler fence: no LDS access or global_load_lds may be
// reordered across it by the optimizer (HW waits are the explicit vmcnt
// plus compiler-tracked lgkmcnt on the frag loads).
__device__ __forceinline__ void barrier_np() {
  __builtin_amdgcn_s_barrier();
  asm volatile("" ::: "memory");
}

// ---- fused fp32 -> bf16 conversion: x | Wq | Wk | Wv -> contiguous dst ------
__global__ __launch_bounds__(256) void convert4_k(
    const float* __restrict__ x, const float* __restrict__ Wq,
    const float* __restrict__ Wk, const float* __restrict__ Wv,
    u16* __restrict__ dst) {
  long g = (long)(blockIdx.x * 256 + threadIdx.x) * 8;   // 8-elem chunks
  const float* s;
  if (g < 8388608L)       s = x  + g;
  else if (g < 9437184L)  s = Wq + (g - 8388608L);
  else if (g < 10485760L) s = Wk + (g - 9437184L);
  else                    s = Wv + (g - 10485760L);
  f32x4 lo = *(const f32x4*)s;
  f32x4 hi = *(const f32x4*)(s + 4);
  s16x8 o;
  #pragma unroll
  for (int e = 0; e < 4; ++e) { o[e] = (short)f2b(lo[e]); o[4 + e] = (short)f2b(hi[e]); }
  *(s16x8*)(dst + g) = o;
}

// ---- NT GEMM, (32*MREP)x256 tile, BK=32, 4-slot LDS ring, 2-phase tiles -----
// Per K-tile T (m201 cadence: reads/stage BEFORE barrier, MFMA cluster after):
//   waitvm<2*CALLS>; barrier      -> tile T landed in LDS for ALL waves;
//                                    all reads of tile T-1 finished (all waves)
//   phase a: ds_read B0..3,A0..HM-1; stage calls [0,SA) of tile T+3
//            barrier; setprio(1); HM*4 MFMA; setprio(0)
//   phase b: ds_read A[HM..MREP); stage calls [SA,CALLS)
//            barrier; setprio(1); HM*4 MFMA; setprio(0)
// Ring safety: stage(T+3) writes slot (T+3)&3 == (T-1)&3, whose last readers
// (tile T-1 phase b) completed before tile T's top barrier.  vmcnt never
// drains to 0 in the loop (2 tiles stay in flight); tail 2C -> C -> 0.
// Bank swizzle (row stride 64 B): LDS chunk (r,c) holds global chunk
// c ^ ((r>>1)&3).  A b128 read's bank group = (4*(lr&1) + q^((lr>>1)&3))&7:
// even frow lanes cover groups 0..3 twice, odd lanes 4..7 twice -> 2-way=free.
// EPI 0: QKV proj (+bias; bf16 Q[b][s][h], K[b][s][h], Vt[b][d][s]).
// EPI 1: scores (*1/32, mask==0 -> -inf).  EPI 2: PV -> fp32 out.
template<int EPI, int MREP>
__global__ __launch_bounds__(512, 2) void gemm_nt(
    const u16* __restrict__ A, const u16* __restrict__ B0,
    const u16* __restrict__ W2, const u16* __restrict__ W3,
    int lda, int ldb, int K, long za, long zb, long ze,
    const float* __restrict__ bq, const float* __restrict__ bk, const float* __restrict__ bv,
    u16* __restrict__ qw, u16* __restrict__ kw, u16* __restrict__ vt,
    const int* __restrict__ mask, u16* __restrict__ sc, float* __restrict__ outO)
{
  constexpr int BM    = 32 * MREP;       // 128 or 256
  constexpr int ACH   = BM * 4;          // A 16B-chunks per K-tile (4/row)
  constexpr int CH    = ACH + 1024;      // + B: 256 rows * 4 chunks
  constexpr int CALLS = CH / 512;        // 3 (MREP=4) or 4 (MREP=8)
  constexpr int SA    = 2;               // stage calls in phase a
  constexpr int SLOT  = CH * 8;          // u16 per ring slot (CH*16 bytes)
  constexpr int HM    = MREP / 2;
  __shared__ __align__(16) u16 lds[4 * SLOT];   // 96 KB or 128 KB

  const int tid  = threadIdx.x;
  const int wave = tid >> 6, lane = tid & 63;
  const int wr = wave >> 2, wc = wave & 3;          // 2 x 4 wave grid
  const int m0 = blockIdx.y * BM, n0 = blockIdx.x * 256;
  const long z = blockIdx.z;
  A += z * za;

  const u16* Bsrc = B0;
  int nbase = n0;
  if constexpr (EPI == 0) {
    Bsrc = (n0 < 1024) ? B0 : (n0 < 2048) ? W2 : W3;
    nbase = n0 & 1023;
  }
  Bsrc += z * zb;

  // per-call staging source pointers (at k=0) and linear LDS offsets.
  // global source is per-lane (swizzled); LDS dest is linear (HW lane*16B).
  const u16* gsrc[CALLS];
  u32 loff[CALLS];
  #pragma unroll
  for (int c = 0; c < CALLS; ++c) {
    int qq  = c * 512 + tid;             // 16B chunk id within tile
    int isB = qq >= ACH;
    int r   = (isB ? qq - ACH : qq) >> 2;
    int kc  = (qq & 3) ^ ((r >> 1) & 3); // XOR-swizzled source chunk
    gsrc[c] = (isB ? (Bsrc + (size_t)(nbase + r) * ldb)
                   : (A    + (size_t)(m0    + r) * lda)) + kc * 8;
    loff[c] = (u32)qq * 8;
  }

  // fragment read offsets (u16 units, relative to ring-slot base)
  const int frow = lane & 15;            // m (or n) index within 16x16 tile
  const int q    = lane >> 4;            // k-quarter (8 elems)
  u32 aoff[MREP], boff[4];
  #pragma unroll
  for (int i = 0; i < MREP; ++i) {
    int lr = wr * (16 * MREP) + i * 16 + frow;
    aoff[i] = (u32)lr * 32 + (u32)((q ^ ((lr >> 1) & 3)) << 3);
  }
  #pragma unroll
  for (int j = 0; j < 4; ++j) {
    int lc = wc * 64 + j * 16 + frow;
    boff[j] = (u32)ACH * 8 + (u32)lc * 32 + (u32)((q ^ ((lc >> 1) & 3)) << 3);
  }

  f32x4 acc[MREP][4];
  const f32x4 fz = {0.f, 0.f, 0.f, 0.f};
  #pragma unroll
  for (int i = 0; i < MREP; ++i)
    #pragma unroll
    for (int j = 0; j < 4; ++j) acc[i][j] = fz;

  const int NT = K >> 5;                 // BK=32 tiles; NT is 32 or 64

  auto stage_full = [&](int t) {
    u16* b = lds + (size_t)(t & 3) * SLOT;
    #pragma unroll
    for (int c = 0; c < CALLS; ++c)
      gl_lds16(gsrc[c] + (size_t)t * 32, b + loff[c]);
  };

  s16x8 bf[4];                           // B frags persist across both phases
  auto tile_body = [&](int T, bool do_stage) {
    const u16* buf = lds + (size_t)(T & 3) * SLOT;
    u16* sb = lds + (size_t)((T + 3) & 3) * SLOT;
    const size_t koff = (size_t)(T + 3) * 32;
    // ---- phase a: reads + stage, then barrier, then MFMA cluster ----
    s16x8 af[HM];
    #pragma unroll
    for (int j = 0; j < 4; ++j) bf[j] = *(const s16x8*)(buf + boff[j]);
    #pragma unroll
    for (int i = 0; i < HM; ++i) af[i] = *(const s16x8*)(buf + aoff[i]);
    if (do_stage) {
      #pragma unroll
      for (int c = 0; c < SA; ++c) gl_lds16(gsrc[c] + koff, sb + loff[c]);
    }
    barrier_np();
    __builtin_amdgcn_s_setprio(1);
    #pragma unroll
    for (int i = 0; i < HM; ++i)
      #pragma unroll
      for (int j = 0; j < 4; ++j)
        acc[i][j] = __builtin_amdgcn_mfma_f32_16x16x32_bf16(af[i], bf[j], acc[i][j], 0, 0, 0);
    __builtin_amdgcn_s_setprio(0);
    // ---- phase b ----
    s16x8 ag[HM];
    #pragma unroll
    for (int i = 0; i < HM; ++i) ag[i] = *(const s16x8*)(buf + aoff[HM + i]);
    if (do_stage) {
      #pragma unroll
      for (int c = SA; c < CALLS; ++c) gl_lds16(gsrc[c] + koff, sb + loff[c]);
    }
    barrier_np();
    __builtin_amdgcn_s_setprio(1);
    #pragma unroll
    for (int i = 0; i < HM; ++i)
      #pragma unroll
      for (int j = 0; j < 4; ++j)
        acc[HM + i][j] = __builtin_amdgcn_mfma_f32_16x16x32_bf16(ag[i], bf[j], acc[HM + i][j], 0, 0, 0);
    __builtin_amdgcn_s_setprio(0);
  };

  stage_full(0); stage_full(1); stage_full(2);   // 3 tiles in flight
  for (int T = 0; T < NT - 3; ++T) {
    waitvm<2 * CALLS>();                 // tile T landed (mine)
    barrier_np();                        // tile T landed (everyone's)
    tile_body(T, true);                  // stages tile T+3 -> slot (T-1)&3
  }
  waitvm<2 * CALLS>(); barrier_np(); tile_body(NT - 3, false);
  waitvm<CALLS>();     barrier_np(); tile_body(NT - 2, false);
  waitvm<0>();         barrier_np(); tile_body(NT - 1, false);

  // epilogue: C/D layout col=lane&15, row=(lane>>4)*4+reg  (m89-verified)
  const int r0 = (lane >> 4) * 4;
  const int ccol = lane & 15;
  #pragma unroll
  for (int i = 0; i < MREP; ++i) {
    #pragma unroll
    for (int j = 0; j < 4; ++j) {
      #pragma unroll
      for (int r = 0; r < 4; ++r) {
        int R = m0 + wr * (16 * MREP) + i * 16 + r0 + r;  // row: (b,)s / q idx
        int C = n0 + wc * 64 + j * 16 + ccol;             // col: feature/k/d
        float v = acc[i][j][r];
        if constexpr (EPI == 0) {
          int sec = C >> 10, nl = C & 1023;
          v += (sec == 0) ? bq[nl] : (sec == 1) ? bk[nl] : bv[nl];
          u16 o = f2b(v);
          int b = R >> 11, s = R & 2047;
          if (sec == 0)      qw[(size_t)R * 1024 + nl] = o;               // Q[b][s][h]
          else if (sec == 1) kw[(size_t)R * 1024 + nl] = o;               // K[b][s][h]
          else               vt[(size_t)b * 2097152u + (size_t)nl * 2048 + s] = o; // Vt[b][d][s]
        } else if constexpr (EPI == 1) {
          v *= 0.03125f;  // 1/sqrt(1024)
          size_t idx = (size_t)(z * ze) + (size_t)R * 2048 + C;
          if (mask[idx] == 0) v = -__builtin_inff();
          sc[idx] = f2b(v);
        } else {
          outO[(size_t)(z * ze) + (size_t)R * 1024 + C] = v;   // fp32 out
        }
      }
    }
  }
}

// ---- row softmax over 2048 bf16, in place, fp32 internal --------------------
__global__ __launch_bounds__(256) void softmax_k(u16* __restrict__ Sc) {
  __shared__ float red[8];
  u16* p = Sc + (size_t)blockIdx.x * 2048;
  const int tid = threadIdx.x;
  const int lane = tid & 63, wv = tid >> 6;
  s16x8 u = *(const s16x8*)(p + tid * 8);
  float v[8];
  #pragma unroll
  for (int e = 0; e < 8; ++e) v[e] = b2f((u16)u[e]);
  float mx = v[0];
  #pragma unroll
  for (int e = 1; e < 8; ++e) mx = fmaxf(mx, v[e]);
  #pragma unroll
  for (int off = 32; off > 0; off >>= 1) mx = fmaxf(mx, __shfl_xor(mx, off));
  if (lane == 0) red[wv] = mx;
  __syncthreads();
  mx = fmaxf(fmaxf(red[0], red[1]), fmaxf(red[2], red[3]));
  float s = 0.f;
  #pragma unroll
  for (int e = 0; e < 8; ++e) { v[e] = __expf(v[e] - mx); s += v[e]; }
  #pragma unroll
  for (int off = 32; off > 0; off >>= 1) s += __shfl_xor(s, off);
  if (lane == 0) red[4 + wv] = s;
  __syncthreads();
  s = (red[4] + red[5]) + (red[6] + red[7]);
  float inv = 1.f / s;
  s16x8 o;
  #pragma unroll
  for (int e = 0; e < 8; ++e) o[e] = (short)f2b(v[e] * inv);
  *(s16x8*)(p + tid * 8) = o;
}

extern "C" void kernel_launch(void* const* d_in, const int* in_sizes, int n_in,
                              void* d_out, int out_size, void* d_ws, size_t ws_size,
                              hipStream_t stream) {
  const float* x  = (const float*)d_in[0];
  const int* mask = (const int*)d_in[1];
  const float* Wq = (const float*)d_in[2];
  const float* bq = (const float*)d_in[3];
  const float* Wk = (const float*)d_in[4];
  const float* bk = (const float*)d_in[5];
  const float* Wv = (const float*)d_in[6];
  const float* bv = (const float*)d_in[7];
  float* out = (float*)d_out;
  char* ws = (char*)d_ws;   // ws_size >= 104 MB established previously

  u16* xc  = (u16*)ws;                   // [8192][1024]  16 MB
  u16* Wqc = (u16*)(ws + (16u << 20));   // 2 MB each (contiguous after xc)
  u16* Wkc = (u16*)(ws + (18u << 20));
  u16* Wvc = (u16*)(ws + (20u << 20));
  u16* Qw  = (u16*)(ws + (22u << 20));   // [4][2048][1024] 16 MB
  u16* Kw  = (u16*)(ws + (38u << 20));   // 16 MB
  u16* Vt  = (u16*)(ws + (54u << 20));   // [4][1024][2048] 16 MB
  u16* Sc  = (u16*)(ws + (70u << 20));   // [4][2048][2048] 32 MB -> 102 MB

  convert4_k<<<5632, 256, 0, stream>>>(x, Wq, Wk, Wv, xc);

  // QKV: M=8192 (b,s), N=3072 (q|k|v), K=1024.  256x256 tiles -> 384 blocks
  gemm_nt<0, 8><<<dim3(12, 32, 1), 512, 0, stream>>>(
      xc, Wqc, Wkc, Wvc, 1024, 1024, 1024, 0, 0, 0,
      bq, bk, bv, Qw, Kw, Vt, nullptr, nullptr, nullptr);
  // scores: per-z M=2048 (q), N=2048 (k), K=1024.  256x256 -> 256 blocks
  gemm_nt<1, 8><<<dim3(8, 8, 4), 512, 0, stream>>>(
      Qw, Kw, nullptr, nullptr, 1024, 1024, 1024, 2097152, 2097152, 4194304,
      nullptr, nullptr, nullptr, nullptr, nullptr, nullptr, mask, Sc, nullptr);
  softmax_k<<<8192, 256, 0, stream>>>(Sc);
  // PV: per-z M=2048 (q), N=1024 (d), K=2048.  128x256 -> 256 blocks
  gemm_nt<2, 4><<<dim3(4, 16, 4), 512, 0, stream>>>(
      Sc, Vt, nullptr, nullptr, 2048, 2048, 2048, 4194304, 2097152, 2097152,
      nullptr, nullptr, nullptr, nullptr, nullptr, nullptr, nullptr, nullptr, out);
}